// Round 2
// baseline (1946.299 us; speedup 1.0000x reference)
//
#include <hip/hip_runtime.h>
#include <hip/hip_bf16.h>

// Problem constants (from reference): B=4, S=1024, F=1024, E=8, K=2, H=4*F=4096
constexpr int Ff = 1024;
constexpr int Ee = 8;
constexpr int Hh = 4096;
constexpr int T  = 4096;        // B*S tokens
constexpr int TM = 64, TN = 64, TK = 16;

__device__ __forceinline__ float gelu_tanh(float v) {
  const float c = 0.7978845608028654f;  // sqrt(2/pi)
  float t = tanhf(c * (v + 0.044715f * v * v * v));
  return 0.5f * v * (1.0f + t);
}

__device__ __forceinline__ float bf2f(unsigned short u) {
  unsigned int v = ((unsigned int)u) << 16;
  return __uint_as_float(v);
}

// ---------------- Gating: one wave (64 lanes) per token ----------------
__global__ __launch_bounds__(256) void gating_kernel(
    const float* __restrict__ x, const float* __restrict__ Wg,
    const float* __restrict__ bg, int* __restrict__ cnt,
    int* __restrict__ list, float* __restrict__ wlist) {
  const int wave = threadIdx.x >> 6;
  const int lane = threadIdx.x & 63;
  const int t = blockIdx.x * 4 + wave;   // grid = T/4 blocks of 4 waves
  float acc[Ee] = {0.f,0.f,0.f,0.f,0.f,0.f,0.f,0.f};
  const float* xrow = x + (size_t)t * Ff;
  for (int f0 = 0; f0 < Ff; f0 += 64) {
    float xv = xrow[f0 + lane];
    const float* wrow = Wg + (size_t)(f0 + lane) * Ee;
    float4 w0 = *reinterpret_cast<const float4*>(wrow);
    float4 w1 = *reinterpret_cast<const float4*>(wrow + 4);
    acc[0] += xv * w0.x; acc[1] += xv * w0.y;
    acc[2] += xv * w0.z; acc[3] += xv * w0.w;
    acc[4] += xv * w1.x; acc[5] += xv * w1.y;
    acc[6] += xv * w1.z; acc[7] += xv * w1.w;
  }
#pragma unroll
  for (int e = 0; e < Ee; ++e) {
#pragma unroll
    for (int off = 32; off; off >>= 1) acc[e] += __shfl_xor(acc[e], off);
  }
  if (lane == 0) {
    float l[Ee], m = -1e30f;
#pragma unroll
    for (int e = 0; e < Ee; ++e) { l[e] = acc[e] + bg[e]; m = fmaxf(m, l[e]); }
    float p[Ee], Z = 0.f;
#pragma unroll
    for (int e = 0; e < Ee; ++e) { p[e] = expf(l[e] - m); Z += p[e]; }
#pragma unroll
    for (int e = 0; e < Ee; ++e) p[e] /= Z;
    // top-2, ties -> lower index (matches jax.lax.top_k stability)
    int i1 = 0; float p1 = p[0];
#pragma unroll
    for (int e = 1; e < Ee; ++e) if (p[e] > p1) { p1 = p[e]; i1 = e; }
    int i2 = -1; float p2 = -1e30f;
#pragma unroll
    for (int e = 0; e < Ee; ++e) if (e != i1 && p[e] > p2) { p2 = p[e]; i2 = e; }
    float denom = p1 + p2 + 1e-8f;
    int pos = atomicAdd(&cnt[i1], 1);
    list[i1 * T + pos] = t; wlist[i1 * T + pos] = p1 / denom;
    pos = atomicAdd(&cnt[i2], 1);
    list[i2 * T + pos] = t; wlist[i2 * T + pos] = p2 / denom;
  }
}

__global__ void prefix_kernel(const int* __restrict__ cnt, int* __restrict__ offs) {
  if (threadIdx.x == 0) {
    int s = 0;
    for (int e = 0; e < Ee; ++e) { offs[e] = s; s += cnt[e]; }
  }
}

// ------- GEMM1 (chunked over H): h_c = gelu(x[tokens] @ W1[e][:, chunk] + b1) -------
__global__ __launch_bounds__(256) void gemm1_kernel(
    const float* __restrict__ x, const float* __restrict__ W1,
    const float* __restrict__ b1, const int* __restrict__ cnt,
    const int* __restrict__ offs, const int* __restrict__ list,
    __hip_bfloat16* __restrict__ h, int Hc, int c) {
  const int e = blockIdx.z;
  const int ce = cnt[e];
  const int m0 = blockIdx.y * TM;
  if (m0 >= ce) return;
  const int n0 = blockIdx.x * TN;
  __shared__ float As[TK][TM + 4];
  __shared__ float Bs[TK][TN + 4];
  const int tid = threadIdx.x;
  const int lm = tid >> 2, lk = (tid & 3) << 2;        // A-load: row, k-offset
  const int bk = tid >> 4, bn = (tid & 15) << 2;       // B-load: k-row, n-offset
  const int tx = tid & 15, ty = tid >> 4;              // compute: 16x16 threads
  const int token = (m0 + lm < ce) ? list[e * T + m0 + lm] : -1;
  const float* __restrict__ Bbase = W1 + (size_t)e * Ff * Hh + (size_t)c * Hc + n0;
  float acc[4][4] = {};
  for (int k0 = 0; k0 < Ff; k0 += TK) {
    float4 av = make_float4(0.f, 0.f, 0.f, 0.f);
    if (token >= 0)
      av = *reinterpret_cast<const float4*>(x + (size_t)token * Ff + k0 + lk);
    As[lk + 0][lm] = av.x; As[lk + 1][lm] = av.y;
    As[lk + 2][lm] = av.z; As[lk + 3][lm] = av.w;
    *reinterpret_cast<float4*>(&Bs[bk][bn]) =
        *reinterpret_cast<const float4*>(Bbase + (size_t)(k0 + bk) * Hh + bn);
    __syncthreads();
#pragma unroll
    for (int kk = 0; kk < TK; ++kk) {
      float4 a = *reinterpret_cast<const float4*>(&As[kk][ty * 4]);
      float4 b = *reinterpret_cast<const float4*>(&Bs[kk][tx * 4]);
      acc[0][0] += a.x * b.x; acc[0][1] += a.x * b.y; acc[0][2] += a.x * b.z; acc[0][3] += a.x * b.w;
      acc[1][0] += a.y * b.x; acc[1][1] += a.y * b.y; acc[1][2] += a.y * b.z; acc[1][3] += a.y * b.w;
      acc[2][0] += a.z * b.x; acc[2][1] += a.z * b.y; acc[2][2] += a.z * b.z; acc[2][3] += a.z * b.w;
      acc[3][0] += a.w * b.x; acc[3][1] += a.w * b.y; acc[3][2] += a.w * b.z; acc[3][3] += a.w * b.w;
    }
    __syncthreads();
  }
  const int grow0 = offs[e] + m0;
  const float* b1e = b1 + (size_t)e * Hh + (size_t)c * Hc + n0 + tx * 4;
#pragma unroll
  for (int i = 0; i < 4; ++i) {
    const int m = ty * 4 + i;
    if (m0 + m >= ce) continue;
    __hip_bfloat16* hp = h + (size_t)(grow0 + m) * Hc + n0 + tx * 4;
    ushort4 pack;
    unsigned short bits[4];
#pragma unroll
    for (int j = 0; j < 4; ++j) {
      float v = acc[i][j] + b1e[j];
      v = gelu_tanh(v);
      __hip_bfloat16 hb = __float2bfloat16(v);
      bits[j] = *reinterpret_cast<unsigned short*>(&hb);
    }
    pack.x = bits[0]; pack.y = bits[1]; pack.z = bits[2]; pack.w = bits[3];
    *reinterpret_cast<ushort4*>(hp) = pack;
  }
}

// --- GEMM2 (chunked): out[token] += w * (h_c @ W2[e][chunk,:] (+ b2 on last chunk)) ---
__global__ __launch_bounds__(256) void gemm2_kernel(
    const __hip_bfloat16* __restrict__ h, const float* __restrict__ W2,
    const float* __restrict__ b2, const int* __restrict__ cnt,
    const int* __restrict__ offs, const int* __restrict__ list,
    const float* __restrict__ wlist, float* __restrict__ out,
    int Hc, int c, int addBias) {
  const int e = blockIdx.z;
  const int ce = cnt[e];
  const int m0 = blockIdx.y * TM;
  if (m0 >= ce) return;
  const int n0 = blockIdx.x * TN;
  __shared__ float As[TK][TM + 4];
  __shared__ float Bs[TK][TN + 4];
  const int tid = threadIdx.x;
  const int lm = tid >> 2, lk = (tid & 3) << 2;
  const int bk = tid >> 4, bn = (tid & 15) << 2;
  const int tx = tid & 15, ty = tid >> 4;
  const bool avalid = (m0 + lm < ce);
  const size_t arow = (size_t)(offs[e] + m0 + lm);
  const float* __restrict__ Bbase =
      W2 + (size_t)e * Hh * Ff + (size_t)c * Hc * Ff + n0;
  float acc[4][4] = {};
  for (int k0 = 0; k0 < Hc; k0 += TK) {
    float a0 = 0.f, a1 = 0.f, a2 = 0.f, a3 = 0.f;
    if (avalid) {
      ushort4 raw = *reinterpret_cast<const ushort4*>(h + arow * Hc + k0 + lk);
      a0 = bf2f(raw.x); a1 = bf2f(raw.y); a2 = bf2f(raw.z); a3 = bf2f(raw.w);
    }
    As[lk + 0][lm] = a0; As[lk + 1][lm] = a1;
    As[lk + 2][lm] = a2; As[lk + 3][lm] = a3;
    *reinterpret_cast<float4*>(&Bs[bk][bn]) =
        *reinterpret_cast<const float4*>(Bbase + (size_t)(k0 + bk) * Ff + bn);
    __syncthreads();
#pragma unroll
    for (int kk = 0; kk < TK; ++kk) {
      float4 a = *reinterpret_cast<const float4*>(&As[kk][ty * 4]);
      float4 b = *reinterpret_cast<const float4*>(&Bs[kk][tx * 4]);
      acc[0][0] += a.x * b.x; acc[0][1] += a.x * b.y; acc[0][2] += a.x * b.z; acc[0][3] += a.x * b.w;
      acc[1][0] += a.y * b.x; acc[1][1] += a.y * b.y; acc[1][2] += a.y * b.z; acc[1][3] += a.y * b.w;
      acc[2][0] += a.z * b.x; acc[2][1] += a.z * b.y; acc[2][2] += a.z * b.z; acc[2][3] += a.z * b.w;
      acc[3][0] += a.w * b.x; acc[3][1] += a.w * b.y; acc[3][2] += a.w * b.z; acc[3][3] += a.w * b.w;
    }
    __syncthreads();
  }
  const float* b2e = b2 + (size_t)e * Ff + n0 + tx * 4;
#pragma unroll
  for (int i = 0; i < 4; ++i) {
    const int m = ty * 4 + i;
    if (m0 + m >= ce) continue;
    const int token = list[e * T + m0 + m];
    const float w = wlist[e * T + m0 + m];
    float* op = out + (size_t)token * Ff + n0 + tx * 4;
#pragma unroll
    for (int j = 0; j < 4; ++j) {
      float v = acc[i][j];
      if (addBias) v += b2e[j];
      atomicAdd(&op[j], w * v);
    }
  }
}

extern "C" void kernel_launch(void* const* d_in, const int* in_sizes, int n_in,
                              void* d_out, int out_size, void* d_ws, size_t ws_size,
                              hipStream_t stream) {
  const float* x  = (const float*)d_in[0];
  const float* Wg = (const float*)d_in[1];
  const float* bg = (const float*)d_in[2];
  const float* W1 = (const float*)d_in[3];
  const float* b1 = (const float*)d_in[4];
  const float* W2 = (const float*)d_in[5];
  const float* b2 = (const float*)d_in[6];
  float* out = (float*)d_out;

  char* ws = (char*)d_ws;
  int*   cnt   = (int*)(ws + 0);                    // 8 ints
  int*   offs  = (int*)(ws + 64);                   // 8 ints
  int*   list  = (int*)(ws + 1024);                 // 8*4096 ints  = 128 KB
  float* wlist = (float*)(ws + 1024 + T * Ee * 4);  // 8*4096 floats = 128 KB
  __hip_bfloat16* h = (__hip_bfloat16*)(ws + (1 << 19));

  // Adaptive H-chunking so the bf16 h buffer fits in ws:
  // full h = (T*K rows = 8192) x Hh x 2B = 64 MiB; per-chunk = 64MiB/nchunk.
  const size_t h_full = (size_t)(T * 2) * Hh * sizeof(__hip_bfloat16);
  int nchunk = 1;
  while (nchunk < 64 && (size_t)(1 << 19) + h_full / nchunk > ws_size) nchunk <<= 1;
  const int Hc = Hh / nchunk;

  hipMemsetAsync(d_out, 0, (size_t)out_size * sizeof(float), stream);
  hipMemsetAsync(cnt, 0, 64, stream);

  gating_kernel<<<T / 4, 256, 0, stream>>>(x, Wg, bg, cnt, list, wlist);
  prefix_kernel<<<1, 64, 0, stream>>>(cnt, offs);
  for (int c = 0; c < nchunk; ++c) {
    gemm1_kernel<<<dim3(Hc / TN, T / TM, Ee), 256, 0, stream>>>(
        x, W1, b1, cnt, offs, list, h, Hc, c);
    gemm2_kernel<<<dim3(Ff / TN, T / TM, Ee), 256, 0, stream>>>(
        h, W2, b2, cnt, offs, list, wlist, out, Hc, c, c == nchunk - 1 ? 1 : 0);
  }
}

// Round 3
// 646.806 us; speedup vs baseline: 3.0091x; 3.0091x over previous
//
#include <hip/hip_runtime.h>
#include <hip/hip_bf16.h>

// Problem constants: B=4, S=1024, F=1024, E=8, K=2, H=4*F=4096
constexpr int Ff = 1024;
constexpr int Ee = 8;
constexpr int Hh = 4096;
constexpr int T  = 4096;        // B*S tokens

typedef short     bf16x8 __attribute__((ext_vector_type(8)));
typedef float     f32x4  __attribute__((ext_vector_type(4)));
typedef unsigned short u16x8 __attribute__((ext_vector_type(8)));

__device__ __forceinline__ float gelu_tanh(float v) {
  const float c = 0.7978845608028654f;  // sqrt(2/pi)
  float t = tanhf(c * (v + 0.044715f * v * v * v));
  return 0.5f * v * (1.0f + t);
}

__device__ __forceinline__ unsigned short bf16bits(float f) {
  __hip_bfloat16 h = __float2bfloat16(f);
  return *reinterpret_cast<unsigned short*>(&h);
}

__device__ __forceinline__ void gl_lds16(const void* g, void* l) {
  __builtin_amdgcn_global_load_lds(
      (const __attribute__((address_space(1))) unsigned int*)g,
      (__attribute__((address_space(3))) unsigned int*)l, 16, 0, 0);
}

// ---------------- Gating (fp32, exact routing) ----------------
__global__ __launch_bounds__(256) void gating_kernel(
    const float* __restrict__ x, const float* __restrict__ Wg,
    const float* __restrict__ bg, int* __restrict__ cnt,
    int* __restrict__ list, float* __restrict__ wlist) {
  const int wave = threadIdx.x >> 6;
  const int lane = threadIdx.x & 63;
  const int t = blockIdx.x * 4 + wave;
  float acc[Ee] = {0.f,0.f,0.f,0.f,0.f,0.f,0.f,0.f};
  const float* xrow = x + (size_t)t * Ff;
  for (int f0 = 0; f0 < Ff; f0 += 64) {
    float xv = xrow[f0 + lane];
    const float* wrow = Wg + (size_t)(f0 + lane) * Ee;
    float4 w0 = *reinterpret_cast<const float4*>(wrow);
    float4 w1 = *reinterpret_cast<const float4*>(wrow + 4);
    acc[0] += xv * w0.x; acc[1] += xv * w0.y;
    acc[2] += xv * w0.z; acc[3] += xv * w0.w;
    acc[4] += xv * w1.x; acc[5] += xv * w1.y;
    acc[6] += xv * w1.z; acc[7] += xv * w1.w;
  }
#pragma unroll
  for (int e = 0; e < Ee; ++e) {
#pragma unroll
    for (int off = 32; off; off >>= 1) acc[e] += __shfl_xor(acc[e], off);
  }
  if (lane == 0) {
    float l[Ee], m = -1e30f;
#pragma unroll
    for (int e = 0; e < Ee; ++e) { l[e] = acc[e] + bg[e]; m = fmaxf(m, l[e]); }
    float p[Ee], Z = 0.f;
#pragma unroll
    for (int e = 0; e < Ee; ++e) { p[e] = expf(l[e] - m); Z += p[e]; }
#pragma unroll
    for (int e = 0; e < Ee; ++e) p[e] /= Z;
    int i1 = 0; float p1 = p[0];
#pragma unroll
    for (int e = 1; e < Ee; ++e) if (p[e] > p1) { p1 = p[e]; i1 = e; }
    int i2 = -1; float p2 = -1e30f;
#pragma unroll
    for (int e = 0; e < Ee; ++e) if (e != i1 && p[e] > p2) { p2 = p[e]; i2 = e; }
    float denom = p1 + p2 + 1e-8f;
    int pos = atomicAdd(&cnt[i1], 1);
    list[i1 * T + pos] = t; wlist[i1 * T + pos] = p1 / denom;
    pos = atomicAdd(&cnt[i2], 1);
    list[i2 * T + pos] = t; wlist[i2 * T + pos] = p2 / denom;
  }
}

__global__ void prefix_kernel(const int* __restrict__ cnt, int* __restrict__ offs) {
  if (threadIdx.x == 0) {
    int s = 0;
    for (int e = 0; e < Ee; ++e) { offs[e] = s; s += cnt[e]; }
  }
}

// ---------------- x fp32 -> bf16 ----------------
__global__ __launch_bounds__(256) void cvt_x_kernel(
    const float* __restrict__ x, unsigned short* __restrict__ xb) {
  const size_t i = ((size_t)blockIdx.x * 256 + threadIdx.x) * 8;
  float4 a = *reinterpret_cast<const float4*>(x + i);
  float4 b = *reinterpret_cast<const float4*>(x + i + 4);
  u16x8 o;
  o[0] = bf16bits(a.x); o[1] = bf16bits(a.y); o[2] = bf16bits(a.z); o[3] = bf16bits(a.w);
  o[4] = bf16bits(b.x); o[5] = bf16bits(b.y); o[6] = bf16bits(b.z); o[7] = bf16bits(b.w);
  *reinterpret_cast<u16x8*>(xb + i) = o;
}

// -------- transpose + convert: dst[e][col][row] (bf16) = src[e][row][col] (fp32) --------
// grid: (cols/64, rows/64, Ee)
__global__ __launch_bounds__(256) void transpose_cvt_kernel(
    const float* __restrict__ src, unsigned short* __restrict__ dst,
    int s_rstride, int d_rstride, size_t s_estride, size_t d_estride) {
  const int e  = blockIdx.z;
  const int r0 = blockIdx.y * 64;
  const int c0 = blockIdx.x * 64;
  __shared__ __align__(16) unsigned short Ts[64][72];  // padded: 144B rows, 16B-aligned
  const int t = threadIdx.x;
  const float* sb = src + (size_t)e * s_estride + (size_t)r0 * s_rstride + c0;
  {
    const int rr = t >> 4;         // 0..15
    const int cc = (t & 15) * 4;   // 0..60
#pragma unroll
    for (int i = 0; i < 4; ++i) {
      float4 v = *reinterpret_cast<const float4*>(sb + (size_t)(rr + i * 16) * s_rstride + cc);
      Ts[cc + 0][rr + i * 16] = bf16bits(v.x);
      Ts[cc + 1][rr + i * 16] = bf16bits(v.y);
      Ts[cc + 2][rr + i * 16] = bf16bits(v.z);
      Ts[cc + 3][rr + i * 16] = bf16bits(v.w);
    }
  }
  __syncthreads();
  {
    const int n  = t >> 2;         // 0..63: dst row (= src col)
    const int ks = (t & 3) * 16;   // 0..48: dst col (= src row) start
    unsigned short* db = dst + (size_t)e * d_estride + (size_t)(c0 + n) * d_rstride + r0 + ks;
    *reinterpret_cast<ulonglong2*>(db)     = *reinterpret_cast<const ulonglong2*>(&Ts[n][ks]);
    *reinterpret_cast<ulonglong2*>(db + 8) = *reinterpret_cast<const ulonglong2*>(&Ts[n][ks + 8]);
  }
}

// ---------------- MFMA GEMM1: h = gelu(xb[tokens] @ W1T^T + b1) ----------------
// A: xb gathered rows [k-fast, K=1024], B: W1T[e][n(chunk)][k-fast 1024]
__global__ __launch_bounds__(256) void gemm1_mfma(
    const unsigned short* __restrict__ xb, const unsigned short* __restrict__ W1T,
    const float* __restrict__ b1, const int* __restrict__ cnt,
    const int* __restrict__ offs, const int* __restrict__ list,
    unsigned short* __restrict__ h, int Hc, int c) {
  const int e  = blockIdx.z;
  const int ce = cnt[e];
  const int m0 = blockIdx.y * 128;
  if (m0 >= ce) return;
  const int n0 = blockIdx.x * 128;
  __shared__ __align__(16) unsigned short As[4][128][8];
  __shared__ __align__(16) unsigned short Bs[4][128][8];
  const int tid = threadIdx.x;
  const int w = tid >> 6, lane = tid & 63;
  const int g = lane >> 4, r16 = lane & 15;
  const int wr = w >> 1, wc = w & 1;
  const int mA0 = m0 + lane, mA1 = m0 + 64 + lane;
  const int tok0 = (mA0 < ce) ? list[e * T + mA0] : 0;
  const int tok1 = (mA1 < ce) ? list[e * T + mA1] : 0;
  const unsigned short* a0p = xb + (size_t)tok0 * Ff + w * 8;
  const unsigned short* a1p = xb + (size_t)tok1 * Ff + w * 8;
  const unsigned short* b0p = W1T + (size_t)e * Hc * Ff + (size_t)(n0 + lane) * Ff + w * 8;
  const unsigned short* b1p = b0p + (size_t)64 * Ff;
  unsigned short* aD0 = &As[0][0][0] + (2 * w + 0) * 512;
  unsigned short* aD1 = &As[0][0][0] + (2 * w + 1) * 512;
  unsigned short* bD0 = &Bs[0][0][0] + (2 * w + 0) * 512;
  unsigned short* bD1 = &Bs[0][0][0] + (2 * w + 1) * 512;
  f32x4 acc[4][4] = {};
  for (int k0 = 0; k0 < Ff; k0 += 32) {
    gl_lds16(a0p + k0, aD0);
    gl_lds16(a1p + k0, aD1);
    gl_lds16(b0p + k0, bD0);
    gl_lds16(b1p + k0, bD1);
    __syncthreads();
    bf16x8 af[4], bfr[4];
#pragma unroll
    for (int i = 0; i < 4; ++i) {
      af[i]  = *reinterpret_cast<const bf16x8*>(&As[g][wr * 64 + i * 16 + r16][0]);
      bfr[i] = *reinterpret_cast<const bf16x8*>(&Bs[g][wc * 64 + i * 16 + r16][0]);
    }
#pragma unroll
    for (int mi = 0; mi < 4; ++mi)
#pragma unroll
      for (int ni = 0; ni < 4; ++ni)
        acc[mi][ni] = __builtin_amdgcn_mfma_f32_16x16x32_bf16(
            af[mi], bfr[ni], acc[mi][ni], 0, 0, 0);
    __syncthreads();
  }
  const int grow0 = offs[e] + m0 + wr * 64;
  const int mrow_base = m0 + wr * 64;
#pragma unroll
  for (int ni = 0; ni < 4; ++ni) {
    const int col = n0 + wc * 64 + ni * 16 + r16;   // col within chunk
    const float bias = b1[(size_t)e * Hh + (size_t)c * Hc + col];
#pragma unroll
    for (int mi = 0; mi < 4; ++mi) {
#pragma unroll
      for (int r = 0; r < 4; ++r) {
        const int m = mi * 16 + g * 4 + r;
        if (mrow_base + m < ce) {
          float v = gelu_tanh(acc[mi][ni][r] + bias);
          h[(size_t)(grow0 + m) * Hc + col] = bf16bits(v);
        }
      }
    }
  }
}

// ---------------- MFMA GEMM2: out[token] += w * (h @ W2T^T (+ b2)) ----------------
__global__ __launch_bounds__(256) void gemm2_mfma(
    const unsigned short* __restrict__ h, const unsigned short* __restrict__ W2T,
    const float* __restrict__ b2, const int* __restrict__ cnt,
    const int* __restrict__ offs, const int* __restrict__ list,
    const float* __restrict__ wlist, float* __restrict__ out,
    int Hc, int addBias) {
  const int e  = blockIdx.z;
  const int ce = cnt[e];
  const int m0 = blockIdx.y * 128;
  if (m0 >= ce) return;
  const int n0 = blockIdx.x * 128;
  __shared__ __align__(16) unsigned short As[4][128][8];
  __shared__ __align__(16) unsigned short Bs[4][128][8];
  const int tid = threadIdx.x;
  const int w = tid >> 6, lane = tid & 63;
  const int g = lane >> 4, r16 = lane & 15;
  const int wr = w >> 1, wc = w & 1;
  const int hr0 = min(offs[e] + m0 + lane,      2 * T - 1);
  const int hr1 = min(offs[e] + m0 + 64 + lane, 2 * T - 1);
  const unsigned short* a0p = h + (size_t)hr0 * Hc + w * 8;
  const unsigned short* a1p = h + (size_t)hr1 * Hc + w * 8;
  const unsigned short* b0p = W2T + (size_t)e * Ff * Hc + (size_t)(n0 + lane) * Hc + w * 8;
  const unsigned short* b1p = b0p + (size_t)64 * Hc;
  unsigned short* aD0 = &As[0][0][0] + (2 * w + 0) * 512;
  unsigned short* aD1 = &As[0][0][0] + (2 * w + 1) * 512;
  unsigned short* bD0 = &Bs[0][0][0] + (2 * w + 0) * 512;
  unsigned short* bD1 = &Bs[0][0][0] + (2 * w + 1) * 512;
  f32x4 acc[4][4] = {};
  for (int k0 = 0; k0 < Hc; k0 += 32) {
    gl_lds16(a0p + k0, aD0);
    gl_lds16(a1p + k0, aD1);
    gl_lds16(b0p + k0, bD0);
    gl_lds16(b1p + k0, bD1);
    __syncthreads();
    bf16x8 af[4], bfr[4];
#pragma unroll
    for (int i = 0; i < 4; ++i) {
      af[i]  = *reinterpret_cast<const bf16x8*>(&As[g][wr * 64 + i * 16 + r16][0]);
      bfr[i] = *reinterpret_cast<const bf16x8*>(&Bs[g][wc * 64 + i * 16 + r16][0]);
    }
#pragma unroll
    for (int mi = 0; mi < 4; ++mi)
#pragma unroll
      for (int ni = 0; ni < 4; ++ni)
        acc[mi][ni] = __builtin_amdgcn_mfma_f32_16x16x32_bf16(
            af[mi], bfr[ni], acc[mi][ni], 0, 0, 0);
    __syncthreads();
  }
  const int mrow_base = m0 + wr * 64;
#pragma unroll
  for (int mi = 0; mi < 4; ++mi) {
#pragma unroll
    for (int r = 0; r < 4; ++r) {
      const int m = mrow_base + mi * 16 + g * 4 + r;
      if (m >= ce) continue;
      const int token = list[e * T + m];
      const float wgt = wlist[e * T + m];
      float* op = out + (size_t)token * Ff;
#pragma unroll
      for (int ni = 0; ni < 4; ++ni) {
        const int col = n0 + wc * 64 + ni * 16 + r16;
        float v = acc[mi][ni][r];
        if (addBias) v += b2[(size_t)e * Ff + col];
        atomicAdd(&op[col], wgt * v);
      }
    }
  }
}

extern "C" void kernel_launch(void* const* d_in, const int* in_sizes, int n_in,
                              void* d_out, int out_size, void* d_ws, size_t ws_size,
                              hipStream_t stream) {
  const float* x  = (const float*)d_in[0];
  const float* Wg = (const float*)d_in[1];
  const float* bg = (const float*)d_in[2];
  const float* W1 = (const float*)d_in[3];
  const float* b1 = (const float*)d_in[4];
  const float* W2 = (const float*)d_in[5];
  const float* b2 = (const float*)d_in[6];
  float* out = (float*)d_out;

  // Adaptive H-chunk: fixed = 8.64MB (lists + xb), per-Hc = 48KB (W1T+W2T+h)
  const size_t fixed = 512 + 2 * (size_t)T * Ee * 4 + (size_t)T * Ff * 2;
  int Hc = 4096;
  while (Hc > 128 && fixed + (size_t)Hc * 49152 > ws_size) Hc >>= 1;
  const int nchunk = Hh / Hc;

  char* p = (char*)d_ws;
  int*   cnt   = (int*)p;            p += 256;
  int*   offs  = (int*)p;            p += 256;
  int*   list  = (int*)p;            p += (size_t)T * Ee * 4;
  float* wlist = (float*)p;          p += (size_t)T * Ee * 4;
  unsigned short* xb  = (unsigned short*)p;  p += (size_t)T * Ff * 2;
  unsigned short* W1T = (unsigned short*)p;  p += (size_t)Ee * Hc * Ff * 2;
  unsigned short* W2T = (unsigned short*)p;  p += (size_t)Ee * Ff * Hc * 2;
  unsigned short* h   = (unsigned short*)p;

  hipMemsetAsync(d_out, 0, (size_t)out_size * sizeof(float), stream);
  hipMemsetAsync(cnt, 0, 64, stream);

  gating_kernel<<<T / 4, 256, 0, stream>>>(x, Wg, bg, cnt, list, wlist);
  prefix_kernel<<<1, 64, 0, stream>>>(cnt, offs);
  cvt_x_kernel<<<(T * Ff) / 2048, 256, 0, stream>>>(x, xb);

  for (int c = 0; c < nchunk; ++c) {
    // W1 chunk: src rows k=1024, cols n in [c*Hc, c*Hc+Hc) -> W1T[e][n'][k]
    transpose_cvt_kernel<<<dim3(Hc / 64, Ff / 64, Ee), 256, 0, stream>>>(
        W1 + (size_t)c * Hc, W1T, Hh, Ff, (size_t)Ff * Hh, (size_t)Hc * Ff);
    // W2 chunk: src rows hh in [c*Hc, ...), cols f=1024 -> W2T[e][f][hh']
    transpose_cvt_kernel<<<dim3(Ff / 64, Hc / 64, Ee), 256, 0, stream>>>(
        W2 + (size_t)c * Hc * Ff, W2T, Ff, Hc, (size_t)Hh * Ff, (size_t)Ff * Hc);
    gemm1_mfma<<<dim3(Hc / 128, 32, Ee), 256, 0, stream>>>(
        xb, W1T, b1, cnt, offs, list, h, Hc, c);
    gemm2_mfma<<<dim3(Ff / 128, 32, Ee), 256, 0, stream>>>(
        h, W2T, b2, cnt, offs, list, wlist, out, Hc, c == nchunk - 1 ? 1 : 0);
  }
}

// Round 4
// 620.671 us; speedup vs baseline: 3.1358x; 1.0421x over previous
//
#include <hip/hip_runtime.h>
#include <hip/hip_bf16.h>

// Problem constants: B=4, S=1024, F=1024, E=8, K=2, H=4*F=4096
constexpr int Ff = 1024;
constexpr int Ee = 8;
constexpr int Hh = 4096;
constexpr int T  = 4096;        // B*S tokens
constexpr int MB = 72;          // max padded m-blocks: ceil((8192+8*127)/128)

typedef short     bf16x8 __attribute__((ext_vector_type(8)));
typedef float     f32x4  __attribute__((ext_vector_type(4)));
typedef unsigned short u16x8 __attribute__((ext_vector_type(8)));

__device__ __forceinline__ float gelu_tanh(float v) {
  const float c = 0.7978845608028654f;  // sqrt(2/pi)
  float t = tanhf(c * (v + 0.044715f * v * v * v));
  return 0.5f * v * (1.0f + t);
}

__device__ __forceinline__ unsigned short bf16bits(float f) {
  __hip_bfloat16 h = __float2bfloat16(f);
  return *reinterpret_cast<unsigned short*>(&h);
}

__device__ __forceinline__ void gl_lds16(const void* g, void* l) {
  __builtin_amdgcn_global_load_lds(
      (const __attribute__((address_space(1))) unsigned int*)g,
      (__attribute__((address_space(3))) unsigned int*)l, 16, 0, 0);
}

// ---------------- Gating (fp32, exact routing) ----------------
__global__ __launch_bounds__(256) void gating_kernel(
    const float* __restrict__ x, const float* __restrict__ Wg,
    const float* __restrict__ bg, int* __restrict__ cnt,
    int* __restrict__ list, float* __restrict__ wlist) {
  const int wave = threadIdx.x >> 6;
  const int lane = threadIdx.x & 63;
  const int t = blockIdx.x * 4 + wave;
  float acc[Ee] = {0.f,0.f,0.f,0.f,0.f,0.f,0.f,0.f};
  const float* xrow = x + (size_t)t * Ff;
  for (int f0 = 0; f0 < Ff; f0 += 64) {
    float xv = xrow[f0 + lane];
    const float* wrow = Wg + (size_t)(f0 + lane) * Ee;
    float4 w0 = *reinterpret_cast<const float4*>(wrow);
    float4 w1 = *reinterpret_cast<const float4*>(wrow + 4);
    acc[0] += xv * w0.x; acc[1] += xv * w0.y;
    acc[2] += xv * w0.z; acc[3] += xv * w0.w;
    acc[4] += xv * w1.x; acc[5] += xv * w1.y;
    acc[6] += xv * w1.z; acc[7] += xv * w1.w;
  }
#pragma unroll
  for (int e = 0; e < Ee; ++e) {
#pragma unroll
    for (int off = 32; off; off >>= 1) acc[e] += __shfl_xor(acc[e], off);
  }
  if (lane == 0) {
    float l[Ee], m = -1e30f;
#pragma unroll
    for (int e = 0; e < Ee; ++e) { l[e] = acc[e] + bg[e]; m = fmaxf(m, l[e]); }
    float p[Ee], Z = 0.f;
#pragma unroll
    for (int e = 0; e < Ee; ++e) { p[e] = expf(l[e] - m); Z += p[e]; }
#pragma unroll
    for (int e = 0; e < Ee; ++e) p[e] /= Z;
    int i1 = 0; float p1 = p[0];
#pragma unroll
    for (int e = 1; e < Ee; ++e) if (p[e] > p1) { p1 = p[e]; i1 = e; }
    int i2 = -1; float p2 = -1e30f;
#pragma unroll
    for (int e = 0; e < Ee; ++e) if (e != i1 && p[e] > p2) { p2 = p[e]; i2 = e; }
    float denom = p1 + p2 + 1e-8f;
    int pos = atomicAdd(&cnt[i1], 1);
    list[i1 * T + pos] = t; wlist[i1 * T + pos] = p1 / denom;
    pos = atomicAdd(&cnt[i2], 1);
    list[i2 * T + pos] = t; wlist[i2 * T + pos] = p2 / denom;
  }
}

// 128-aligned expert row offsets (padded flattened row space)
__global__ void prefix_kernel(const int* __restrict__ cnt, int* __restrict__ offs) {
  if (threadIdx.x == 0) {
    int s = 0;
    for (int e = 0; e < Ee; ++e) { offs[e] = s; s += (cnt[e] + 127) & ~127; }
    offs[Ee] = s;
  }
}

// ---------------- x fp32 -> bf16 ----------------
__global__ __launch_bounds__(256) void cvt_x_kernel(
    const float* __restrict__ x, unsigned short* __restrict__ xb) {
  const size_t i = ((size_t)blockIdx.x * 256 + threadIdx.x) * 8;
  float4 a = *reinterpret_cast<const float4*>(x + i);
  float4 b = *reinterpret_cast<const float4*>(x + i + 4);
  u16x8 o;
  o[0] = bf16bits(a.x); o[1] = bf16bits(a.y); o[2] = bf16bits(a.z); o[3] = bf16bits(a.w);
  o[4] = bf16bits(b.x); o[5] = bf16bits(b.y); o[6] = bf16bits(b.z); o[7] = bf16bits(b.w);
  *reinterpret_cast<u16x8*>(xb + i) = o;
}

// -------- transpose + convert: dst[e][col][row] (bf16) = src[e][row][col] (fp32) --------
__global__ __launch_bounds__(256) void transpose_cvt_kernel(
    const float* __restrict__ src, unsigned short* __restrict__ dst,
    int s_rstride, int d_rstride, size_t s_estride, size_t d_estride) {
  const int e  = blockIdx.z;
  const int r0 = blockIdx.y * 64;
  const int c0 = blockIdx.x * 64;
  __shared__ __align__(16) unsigned short Ts[64][72];
  const int t = threadIdx.x;
  const float* sb = src + (size_t)e * s_estride + (size_t)r0 * s_rstride + c0;
  {
    const int rr = t >> 4;
    const int cc = (t & 15) * 4;
#pragma unroll
    for (int i = 0; i < 4; ++i) {
      float4 v = *reinterpret_cast<const float4*>(sb + (size_t)(rr + i * 16) * s_rstride + cc);
      Ts[cc + 0][rr + i * 16] = bf16bits(v.x);
      Ts[cc + 1][rr + i * 16] = bf16bits(v.y);
      Ts[cc + 2][rr + i * 16] = bf16bits(v.z);
      Ts[cc + 3][rr + i * 16] = bf16bits(v.w);
    }
  }
  __syncthreads();
  {
    const int n  = t >> 2;
    const int ks = (t & 3) * 16;
    unsigned short* db = dst + (size_t)e * d_estride + (size_t)(c0 + n) * d_rstride + r0 + ks;
    *reinterpret_cast<ulonglong2*>(db)     = *reinterpret_cast<const ulonglong2*>(&Ts[n][ks]);
    *reinterpret_cast<ulonglong2*>(db + 8) = *reinterpret_cast<const ulonglong2*>(&Ts[n][ks + 8]);
  }
}

// ---------------- GEMM1: h = gelu(xb[tokens] @ W1T^T + b1), 2-phase dbuf ----------------
__global__ __launch_bounds__(256) void gemm1_mfma(
    const unsigned short* __restrict__ xb, const unsigned short* __restrict__ W1T,
    const float* __restrict__ b1, const int* __restrict__ cnt,
    const int* __restrict__ offs, const int* __restrict__ list,
    unsigned short* __restrict__ h, int Hc, int c, int nxg) {
  // XCD-chunked swizzle over flattened (x, y) grid; nwg % 8 == 0
  const int nwg = nxg * MB;
  int bid = blockIdx.x + nxg * blockIdx.y;
  bid = (bid & 7) * (nwg >> 3) + (bid >> 3);
  const int bx = bid % nxg, by = bid / nxg;

  const int m0g = by * 128;
  int e = 0;
#pragma unroll
  for (int i = 1; i < Ee; ++i) e += (m0g >= offs[i]) ? 1 : 0;
  const int ce = cnt[e];
  const int mloc = m0g - offs[e];
  if (mloc >= ce) return;
  const int n0 = bx * 128;

  __shared__ __align__(16) unsigned short As[2][4][128][8];
  __shared__ __align__(16) unsigned short Bs[2][4][128][8];
  const int tid = threadIdx.x;
  const int w = tid >> 6, lane = tid & 63;
  const int g = lane >> 4, r16 = lane & 15;
  const int wr = w >> 1, wc = w & 1;
  const int tok0 = (mloc + lane < ce)      ? list[e * T + mloc + lane]      : 0;
  const int tok1 = (mloc + 64 + lane < ce) ? list[e * T + mloc + 64 + lane] : 0;
  const unsigned short* a0p = xb + (size_t)tok0 * Ff + w * 8;
  const unsigned short* a1p = xb + (size_t)tok1 * Ff + w * 8;
  const unsigned short* b0p = W1T + (size_t)e * Hc * Ff + (size_t)(n0 + lane) * Ff + w * 8;
  const unsigned short* b1p = b0p + (size_t)64 * Ff;

  f32x4 acc[4][4] = {};
  constexpr int nt = Ff / 32;
  auto STAGE = [&](int buf, int kt) {
    const int k0 = kt * 32;
    unsigned short* aB = &As[buf][0][0][0] + w * 1024;
    unsigned short* bB = &Bs[buf][0][0][0] + w * 1024;
    gl_lds16(a0p + k0, aB);
    gl_lds16(a1p + k0, aB + 512);
    gl_lds16(b0p + k0, bB);
    gl_lds16(b1p + k0, bB + 512);
  };
  STAGE(0, 0);
  int cur = 0;
#pragma unroll 1
  for (int t = 0; t < nt; ++t) {
    if (t + 1 < nt) {
      STAGE(cur ^ 1, t + 1);
      asm volatile("s_waitcnt vmcnt(4)" ::: "memory");
    } else {
      asm volatile("s_waitcnt vmcnt(0)" ::: "memory");
    }
    __builtin_amdgcn_s_barrier();
    asm volatile("" ::: "memory");
    bf16x8 af[4], bfr[4];
#pragma unroll
    for (int i = 0; i < 4; ++i) {
      af[i]  = *reinterpret_cast<const bf16x8*>(&As[cur][g][wr * 64 + i * 16 + r16][0]);
      bfr[i] = *reinterpret_cast<const bf16x8*>(&Bs[cur][g][wc * 64 + i * 16 + r16][0]);
    }
    __builtin_amdgcn_s_setprio(1);
#pragma unroll
    for (int mi = 0; mi < 4; ++mi)
#pragma unroll
      for (int ni = 0; ni < 4; ++ni)
        acc[mi][ni] = __builtin_amdgcn_mfma_f32_16x16x32_bf16(
            af[mi], bfr[ni], acc[mi][ni], 0, 0, 0);
    __builtin_amdgcn_s_setprio(0);
    asm volatile("" ::: "memory");
    __builtin_amdgcn_s_barrier();
    cur ^= 1;
  }
  const int colbase = n0 + wc * 64;
#pragma unroll
  for (int ni = 0; ni < 4; ++ni) {
    const int col = colbase + ni * 16 + r16;
    const float bias = b1[(size_t)e * Hh + (size_t)c * Hc + col];
#pragma unroll
    for (int mi = 0; mi < 4; ++mi)
#pragma unroll
      for (int r = 0; r < 4; ++r) {
        const int m = wr * 64 + mi * 16 + g * 4 + r;
        if (mloc + m < ce)
          h[(size_t)(m0g + m) * Hc + col] = bf16bits(gelu_tanh(acc[mi][ni][r] + bias));
      }
  }
}

// -------- GEMM2: out[token] += w * (h @ W2T^T (+b2)), 2-phase dbuf, K-split --------
__global__ __launch_bounds__(256) void gemm2_mfma(
    const unsigned short* __restrict__ h, const unsigned short* __restrict__ W2T,
    const float* __restrict__ b2, const int* __restrict__ cnt,
    const int* __restrict__ offs, const int* __restrict__ list,
    const float* __restrict__ wlist, float* __restrict__ out,
    int Hc, int kLen, int biasC) {
  const int nxg = Ff / 128, nzg = Hc / kLen;
  const int nwg = nxg * MB * nzg;
  int bid = blockIdx.x + nxg * (blockIdx.y + MB * blockIdx.z);
  bid = (bid & 7) * (nwg >> 3) + (bid >> 3);
  const int bx = bid % nxg, by = (bid / nxg) % MB, bz = bid / (nxg * MB);
  const int kOff = bz * kLen;

  const int m0g = by * 128;
  int e = 0;
#pragma unroll
  for (int i = 1; i < Ee; ++i) e += (m0g >= offs[i]) ? 1 : 0;
  const int ce = cnt[e];
  const int mloc = m0g - offs[e];
  if (mloc >= ce) return;
  const int n0 = bx * 128;

  __shared__ __align__(16) unsigned short As[2][4][128][8];
  __shared__ __align__(16) unsigned short Bs[2][4][128][8];
  const int tid = threadIdx.x;
  const int w = tid >> 6, lane = tid & 63;
  const int g = lane >> 4, r16 = lane & 15;
  const int wr = w >> 1, wc = w & 1;
  const unsigned short* a0p = h + (size_t)(m0g + lane) * Hc + kOff + w * 8;
  const unsigned short* a1p = a0p + (size_t)64 * Hc;
  const unsigned short* b0p = W2T + (size_t)e * Ff * Hc + (size_t)(n0 + lane) * Hc + kOff + w * 8;
  const unsigned short* b1p = b0p + (size_t)64 * Hc;

  f32x4 acc[4][4] = {};
  const int nt = kLen / 32;
  auto STAGE = [&](int buf, int kt) {
    const int k0 = kt * 32;
    unsigned short* aB = &As[buf][0][0][0] + w * 1024;
    unsigned short* bB = &Bs[buf][0][0][0] + w * 1024;
    gl_lds16(a0p + k0, aB);
    gl_lds16(a1p + k0, aB + 512);
    gl_lds16(b0p + k0, bB);
    gl_lds16(b1p + k0, bB + 512);
  };
  STAGE(0, 0);
  int cur = 0;
#pragma unroll 1
  for (int t = 0; t < nt; ++t) {
    if (t + 1 < nt) {
      STAGE(cur ^ 1, t + 1);
      asm volatile("s_waitcnt vmcnt(4)" ::: "memory");
    } else {
      asm volatile("s_waitcnt vmcnt(0)" ::: "memory");
    }
    __builtin_amdgcn_s_barrier();
    asm volatile("" ::: "memory");
    bf16x8 af[4], bfr[4];
#pragma unroll
    for (int i = 0; i < 4; ++i) {
      af[i]  = *reinterpret_cast<const bf16x8*>(&As[cur][g][wr * 64 + i * 16 + r16][0]);
      bfr[i] = *reinterpret_cast<const bf16x8*>(&Bs[cur][g][wc * 64 + i * 16 + r16][0]);
    }
    __builtin_amdgcn_s_setprio(1);
#pragma unroll
    for (int mi = 0; mi < 4; ++mi)
#pragma unroll
      for (int ni = 0; ni < 4; ++ni)
        acc[mi][ni] = __builtin_amdgcn_mfma_f32_16x16x32_bf16(
            af[mi], bfr[ni], acc[mi][ni], 0, 0, 0);
    __builtin_amdgcn_s_setprio(0);
    asm volatile("" ::: "memory");
    __builtin_amdgcn_s_barrier();
    cur ^= 1;
  }
  const bool addBias = (biasC != 0) && (bz == 0);
#pragma unroll
  for (int mi = 0; mi < 4; ++mi)
#pragma unroll
    for (int r = 0; r < 4; ++r) {
      const int m = wr * 64 + mi * 16 + g * 4 + r;
      if (mloc + m >= ce) continue;
      const int token = list[e * T + mloc + m];
      const float wgt = wlist[e * T + mloc + m];
      float* op = out + (size_t)token * Ff;
#pragma unroll
      for (int ni = 0; ni < 4; ++ni) {
        const int col = n0 + wc * 64 + ni * 16 + r16;
        float v = acc[mi][ni][r];
        if (addBias) v += b2[(size_t)e * Ff + col];
        atomicAdd(&op[col], wgt * v);
      }
    }
}

extern "C" void kernel_launch(void* const* d_in, const int* in_sizes, int n_in,
                              void* d_out, int out_size, void* d_ws, size_t ws_size,
                              hipStream_t stream) {
  const float* x  = (const float*)d_in[0];
  const float* Wg = (const float*)d_in[1];
  const float* bg = (const float*)d_in[2];
  const float* W1 = (const float*)d_in[3];
  const float* b1 = (const float*)d_in[4];
  const float* W2 = (const float*)d_in[5];
  const float* b2 = (const float*)d_in[6];
  float* out = (float*)d_out;

  // Adaptive H-chunk. fixed = lists + xb; per-Hc-unit = W1T + W2T + h(9216 rows)
  const size_t fixed = 1024 + 2 * (size_t)T * Ee * 4 + (size_t)T * Ff * 2;
  int Hc = 4096;
  while (Hc > 128 && fixed + (size_t)Hc * 51200 > ws_size) Hc >>= 1;
  const int nchunk = Hh / Hc;
  const int ksplit = 2;
  const int kLen = Hc / ksplit;

  char* p = (char*)d_ws;
  int*   cnt   = (int*)p;            p += 512;
  int*   offs  = (int*)p;            p += 512;
  int*   list  = (int*)p;            p += (size_t)T * Ee * 4;
  float* wlist = (float*)p;          p += (size_t)T * Ee * 4;
  unsigned short* xb  = (unsigned short*)p;  p += (size_t)T * Ff * 2;
  unsigned short* W1T = (unsigned short*)p;  p += (size_t)Ee * Hc * Ff * 2;
  unsigned short* W2T = (unsigned short*)p;  p += (size_t)Ee * Ff * Hc * 2;
  unsigned short* h   = (unsigned short*)p;  // 9216 * Hc * 2

  hipMemsetAsync(d_out, 0, (size_t)out_size * sizeof(float), stream);
  hipMemsetAsync(cnt, 0, 64, stream);

  gating_kernel<<<T / 4, 256, 0, stream>>>(x, Wg, bg, cnt, list, wlist);
  prefix_kernel<<<1, 64, 0, stream>>>(cnt, offs);
  cvt_x_kernel<<<(T * Ff) / 2048, 256, 0, stream>>>(x, xb);

  for (int c = 0; c < nchunk; ++c) {
    transpose_cvt_kernel<<<dim3(Hc / 64, Ff / 64, Ee), 256, 0, stream>>>(
        W1 + (size_t)c * Hc, W1T, Hh, Ff, (size_t)Ff * Hh, (size_t)Hc * Ff);
    transpose_cvt_kernel<<<dim3(Ff / 64, Hc / 64, Ee), 256, 0, stream>>>(
        W2 + (size_t)c * Hc * Ff, W2T, Ff, Hc, (size_t)Hh * Ff, (size_t)Ff * Hc);
    gemm1_mfma<<<dim3(Hc / 128, MB), 256, 0, stream>>>(
        xb, W1T, b1, cnt, offs, list, h, Hc, c, Hc / 128);
    gemm2_mfma<<<dim3(Ff / 128, MB, ksplit), 256, 0, stream>>>(
        h, W2T, b2, cnt, offs, list, wlist, out, Hc, kLen,
        c == nchunk - 1 ? 1 : 0);
  }
}